// Round 19
// baseline (190.571 us; speedup 1.0000x reference)
//
#include <hip/hip_runtime.h>

#define EMBED 64
#define IPB   128        // items per bucket (shift 7)
#define MAXNB 256        // max buckets (n_items/IPB = 196)
#define CHUNK 1280       // edges per scatter block (1250 blocks; 5 edges/thread)
#define EPT   5          // edges per thread in scatter
#define CAP   16384      // static per-bucket stage capacity (max real bucket ~8.5k)

// bf16 round-to-nearest-even helpers
__device__ __forceinline__ unsigned int bfr(float x) {
    unsigned int u = __float_as_uint(x);
    return (u + 0x7FFFu + ((u >> 16) & 1u)) >> 16;
}
__device__ __forceinline__ unsigned int pack2(float lo, float hi) {
    return bfr(lo) | (bfr(hi) << 16);
}

// ---------- build kernels ----------

// user rp + user dinv (two binary searches); also zeroes gcnt
__global__ void k_build1(const int* __restrict__ rows, int* __restrict__ rp,
                         float* __restrict__ dinv, int* __restrict__ gcnt,
                         int n_users, int half, int nb) {
    int r = blockIdx.x * blockDim.x + threadIdx.x;
    if (r < nb) gcnt[r] = 0;
    if (r > n_users) return;
    int lo = 0, hi = half;
    while (lo < hi) { int mid = (lo + hi) >> 1; if (rows[mid] < r) lo = mid + 1; else hi = mid; }
    rp[r] = lo;
    if (r < n_users) {
        int lo2 = lo, hi2 = half;
        while (lo2 < hi2) { int mid = (lo2 + hi2) >> 1; if (rows[mid] < r + 1) lo2 = mid + 1; else hi2 = mid; }
        int deg = lo2 - lo;
        dinv[r] = (deg > 0) ? (1.0f / sqrtf((float)deg)) : 0.0f;
    }
}

// fused 3-range kernel:
//  [0, npack)             : pack user-half cols -> u16
//  [npack, npack+nchunk)  : register-staged single-read scatter of item-half chunk
//  [npack+nchunk, +ninit) : user-row init f0 = dinv*e0 (bf16)
__global__ void k_pack_scatter(const int* __restrict__ cols,
                               const int* __restrict__ rows_hi, const int* __restrict__ cols_hi,
                               int* __restrict__ gcnt, unsigned short* __restrict__ col16,
                               unsigned int* __restrict__ stage,
                               const float4* __restrict__ u_emb, const float* __restrict__ dinv,
                               uint2* __restrict__ f0,
                               int n_users, int half, int npack, int nchunk, int ninit,
                               int nb, int n_u_vec) {
    int b = blockIdx.x;
    int tid = threadIdx.x;
    if (b < npack) {
        for (int e = b * 256 + tid; e < half; e += npack * 256)
            col16[e] = (unsigned short)(cols[e] - n_users);
        return;
    }
    b -= npack;
    if (b >= nchunk) {
        int bi = b - nchunk;
        for (int idx = bi * 256 + tid; idx < n_u_vec; idx += ninit * 256) {
            float4 v = u_emb[idx];
            float dv = dinv[idx >> 4];
            uint2 fv; fv.x = pack2(dv * v.x, dv * v.y); fv.y = pack2(dv * v.z, dv * v.w);
            f0[idx] = fv;
        }
        return;
    }
    // ---- scatter: pass A loads edges into registers + LDS histogram ----
    __shared__ int lh[MAXNB];
    __shared__ int cur[MAXNB];
    int beg = b * CHUNK;
    int end = beg + CHUNK; if (end > half) end = half;
    for (int i = tid; i < MAXNB; i += 256) lh[i] = 0;
    __syncthreads();
    unsigned int x[EPT];
    int nvalid = 0;
    #pragma unroll
    for (int k = 0; k < EPT; ++k) {
        int i = beg + tid + k * 256;
        if (i < end) {
            int it = rows_hi[i] - n_users;
            x[k] = ((unsigned int)it << 16) | (unsigned int)cols_hi[i];
            atomicAdd(&lh[it >> 7], 1);
            nvalid = k + 1;
        }
    }
    __syncthreads();
    if (tid < nb) {
        int c = lh[tid];
        int base = c ? atomicAdd(&gcnt[tid], c) : 0;
        cur[tid] = tid * CAP + base;
    }
    __syncthreads();
    // ---- pass B: scatter from registers ----
    #pragma unroll
    for (int k = 0; k < EPT; ++k) {
        if (k < nvalid) {
            int bk = x[k] >> 23;                 // item>>7
            int pos = atomicAdd(&cur[bk], 1);
            stage[pos] = x[k];
        }
    }
}

// one block per bucket: scan gcnt -> own base; hist 128 items; scan -> item rp +
// item dinv; rank into col16; then init this bucket's item rows (f0).
__global__ void k_brank2(const int* __restrict__ gcnt, const unsigned int* __restrict__ stage,
                         unsigned short* __restrict__ col16, int* __restrict__ rp,
                         float* __restrict__ dinv,
                         const float4* __restrict__ i_emb, uint2* __restrict__ f0,
                         int n_users, int n_items, int n_edges, int half, int nb) {
    __shared__ int sums[256];
    __shared__ int hist[IPB];
    __shared__ int scanbuf[IPB];
    __shared__ int cur[IPB];
    __shared__ float sdinv[IPB];
    int k = blockIdx.x;
    int tid = threadIdx.x;

    int v = (tid < nb) ? gcnt[tid] : 0;
    sums[tid] = v;
    __syncthreads();
    for (int o = 1; o < 256; o <<= 1) {
        int t = (tid >= o) ? sums[tid - o] : 0;
        __syncthreads();
        sums[tid] += t;
        __syncthreads();
    }
    int obase = half + sums[k] - gcnt[k];

    int first = k * IPB;
    int nit = n_items - first; if (nit > IPB) nit = IPB;
    int cnt = gcnt[k];
    int sbeg = k * CAP;

    if (tid < IPB) hist[tid] = 0;
    __syncthreads();
    for (int i = tid; i < cnt; i += 256)
        atomicAdd(&hist[(int)(stage[sbeg + i] >> 16) - first], 1);
    __syncthreads();
    if (tid < IPB) scanbuf[tid] = hist[tid];
    __syncthreads();
    for (int o = 1; o < IPB; o <<= 1) {
        int t = (tid < IPB && tid >= o) ? scanbuf[tid - o] : 0;
        __syncthreads();
        if (tid < IPB) scanbuf[tid] += t;
        __syncthreads();
    }
    if (tid < nit) {
        int pos = obase + scanbuf[tid] - hist[tid];
        rp[n_users + first + tid] = pos;
        cur[tid] = pos;
        int deg = hist[tid];
        float dv = (deg > 0) ? (1.0f / sqrtf((float)deg)) : 0.0f;
        dinv[n_users + first + tid] = dv;
        sdinv[tid] = dv;
    }
    if (k == 0 && tid == 0) rp[n_users + n_items] = n_edges;
    __syncthreads();
    for (int i = tid; i < cnt; i += 256) {
        unsigned int x = stage[sbeg + i];
        int il = (int)(x >> 16) - first;
        int pos = atomicAdd(&cur[il], 1);
        col16[pos] = (unsigned short)(x & 0xFFFFu);
    }
    // item-row init (f0 only)
    for (int t2 = tid; t2 < nit * 16; t2 += 256) {
        int i = t2 >> 4, q = t2 & 15;
        float4 v4 = i_emb[(size_t)(first + i) * 16 + q];
        float dv = sdinv[i];
        uint2 fv; fv.x = pack2(dv * v4.x, dv * v4.y); fv.y = pack2(dv * v4.z, dv * v4.w);
        f0[(size_t)(n_users + first + i) * 16 + q] = fv;
    }
}

// ---------- SpMM: FOUR rows per wave (16-lane quarters) ----------
// per quarter: grp = edge slot 0..1, sub = 8-dim slice 0..7
// last=0: fout[row] = bf16(dinv^2 * S)
// last=1: acc[row] = 0.25*(e0 + sqrt(deg)*(f1+f2) + dinv*S)
#define ACC8(sv, g) do { \
    sv[0] += __uint_as_float((g).x << 16); sv[1] += __uint_as_float((g).x & 0xFFFF0000u); \
    sv[2] += __uint_as_float((g).y << 16); sv[3] += __uint_as_float((g).y & 0xFFFF0000u); \
    sv[4] += __uint_as_float((g).z << 16); sv[5] += __uint_as_float((g).z & 0xFFFF0000u); \
    sv[6] += __uint_as_float((g).w << 16); sv[7] += __uint_as_float((g).w & 0xFFFF0000u); \
} while (0)

__global__ void k_spmm(const int* __restrict__ rp, const unsigned short* __restrict__ col16,
                       const float* __restrict__ dinv,
                       const uint4* __restrict__ fin, uint4* __restrict__ fout,
                       const uint4* __restrict__ fl1, const uint4* __restrict__ fl2,
                       const float4* __restrict__ u_emb, const float4* __restrict__ i_emb,
                       float4* __restrict__ acc,
                       int n_users, int n_nodes, int last) {
    int gid = blockIdx.x * blockDim.x + threadIdx.x;
    int wid = gid >> 6;                 // wave index
    int lane = threadIdx.x & 63;
    int qtr  = lane >> 4;               // which row of the quad (0..3)
    int grp  = (lane >> 3) & 1;         // edge slot 0..1
    int sub  = lane & 7;                // 8-dim slice

    int row = wid * 4 + qtr;
    if (row >= n_nodes) return;

    int beg = rp[row], end = rp[row + 1];
    unsigned int sbase = ((row < n_users) ? ((unsigned)n_users << 7) : 0u)
                       + ((unsigned)sub << 4);
    const char* fb = (const char*)fin;

    float s[8] = {0.f, 0.f, 0.f, 0.f, 0.f, 0.f, 0.f, 0.f};
    float t[8] = {0.f, 0.f, 0.f, 0.f, 0.f, 0.f, 0.f, 0.f};

    int j = beg + grp;
    // 8 consecutive edges per iteration (2 slots x stride-2 x unroll-4)
    for (; j + 6 < end; j += 8) {
        unsigned int c0 = col16[j];
        unsigned int c1 = col16[j + 2];
        unsigned int c2 = col16[j + 4];
        unsigned int c3 = col16[j + 6];
        uint4 g0 = *(const uint4*)(fb + ((c0 << 7) + sbase));
        uint4 g1 = *(const uint4*)(fb + ((c1 << 7) + sbase));
        uint4 g2 = *(const uint4*)(fb + ((c2 << 7) + sbase));
        uint4 g3 = *(const uint4*)(fb + ((c3 << 7) + sbase));
        ACC8(s, g0);
        ACC8(t, g1);
        ACC8(s, g2);
        ACC8(t, g3);
    }
    for (; j < end; j += 2) {
        unsigned int c = col16[j];
        uint4 g = *(const uint4*)(fb + ((c << 7) + sbase));
        ACC8(s, g);
    }

    #pragma unroll
    for (int d = 0; d < 8; ++d) s[d] += t[d];
    // reduce across the 2 edge slots (xor 8 stays within the 16-lane quarter)
    #pragma unroll
    for (int d = 0; d < 8; ++d) {
        s[d] += __shfl_xor(s[d], 8, 64);
    }

    if (grp == 0) {
        float dv = dinv[row];
        if (!last) {
            float d2 = dv * dv;
            uint4 fn;
            fn.x = pack2(d2 * s[0], d2 * s[1]);
            fn.y = pack2(d2 * s[2], d2 * s[3]);
            fn.z = pack2(d2 * s[4], d2 * s[5]);
            fn.w = pack2(d2 * s[6], d2 * s[7]);
            fout[row * 8 + sub] = fn;
        } else {
            float sq = sqrtf((float)(end - beg));
            uint4 a = fl1[row * 8 + sub];
            uint4 b = fl2[row * 8 + sub];
            float e12[8];
            e12[0] = __uint_as_float(a.x << 16)         + __uint_as_float(b.x << 16);
            e12[1] = __uint_as_float(a.x & 0xFFFF0000u) + __uint_as_float(b.x & 0xFFFF0000u);
            e12[2] = __uint_as_float(a.y << 16)         + __uint_as_float(b.y << 16);
            e12[3] = __uint_as_float(a.y & 0xFFFF0000u) + __uint_as_float(b.y & 0xFFFF0000u);
            e12[4] = __uint_as_float(a.z << 16)         + __uint_as_float(b.z << 16);
            e12[5] = __uint_as_float(a.z & 0xFFFF0000u) + __uint_as_float(b.z & 0xFFFF0000u);
            e12[6] = __uint_as_float(a.w << 16)         + __uint_as_float(b.w << 16);
            e12[7] = __uint_as_float(a.w & 0xFFFF0000u) + __uint_as_float(b.w & 0xFFFF0000u);
            const float4* src = (row < n_users) ? u_emb : i_emb;
            int r0 = (row < n_users) ? row : row - n_users;
            float4 v0 = src[r0 * 16 + sub * 2];
            float4 v1 = src[r0 * 16 + sub * 2 + 1];
            float4 o0, o1;
            o0.x = 0.25f * (v0.x + sq * e12[0] + dv * s[0]);
            o0.y = 0.25f * (v0.y + sq * e12[1] + dv * s[1]);
            o0.z = 0.25f * (v0.z + sq * e12[2] + dv * s[2]);
            o0.w = 0.25f * (v0.w + sq * e12[3] + dv * s[3]);
            o1.x = 0.25f * (v1.x + sq * e12[4] + dv * s[4]);
            o1.y = 0.25f * (v1.y + sq * e12[5] + dv * s[5]);
            o1.z = 0.25f * (v1.z + sq * e12[6] + dv * s[6]);
            o1.w = 0.25f * (v1.w + sq * e12[7] + dv * s[7]);
            acc[row * 16 + sub * 2]     = o0;
            acc[row * 16 + sub * 2 + 1] = o1;
        }
    }
}

extern "C" void kernel_launch(void* const* d_in, const int* in_sizes, int n_in,
                              void* d_out, int out_size, void* d_ws, size_t ws_size,
                              hipStream_t stream) {
    const float* user_embeds = (const float*)d_in[0];
    const float* item_embeds = (const float*)d_in[1];
    const int*   rows        = (const int*)d_in[3];
    const int*   cols        = (const int*)d_in[4];

    const int n_u_elems = in_sizes[0];            // 50000*64
    const int n_i_elems = in_sizes[1];            // 25000*64
    const int n_total   = n_u_elems + n_i_elems;  // 75000*64
    const int n_edges   = in_sizes[2];            // 3,200,000
    const int half      = n_edges / 2;            // user-sorted half
    const int n_users   = n_u_elems / EMBED;      // 50000
    const int n_nodes   = n_total / EMBED;        // 75000
    const int n_items   = n_nodes - n_users;      // 25000
    const int nb        = (n_items + IPB - 1) / IPB;        // 196
    const int nchunk    = (half + CHUNK - 1) / CHUNK;       // 1250
    const int npack     = 256;
    const int ninit     = 256;

    float* acc = (float*)d_out;

    char* p = (char*)d_ws;
    unsigned int* f0 = (unsigned int*)p;         p += (size_t)n_total * 2;   // bf16
    unsigned int* f1 = (unsigned int*)p;         p += (size_t)n_total * 2;
    unsigned int* f2 = (unsigned int*)p;         p += (size_t)n_total * 2;
    unsigned short* col16 = (unsigned short*)p;  p += (size_t)n_edges * 2;
    unsigned int* stage   = (unsigned int*)p;    p += (size_t)nb * CAP * 4;
    int*   rp     = (int*)p;                     p += (size_t)(n_nodes + 1) * 4;
    float* dinv   = (float*)p;                   p += (size_t)n_nodes * 4;
    int*   gcnt   = (int*)p;

    // ---- build + init: 3 dispatches ----
    {
        int ublocks = (n_users + 1 + 255) / 256;
        k_build1<<<ublocks, 256, 0, stream>>>(rows, rp, dinv, gcnt, n_users, half, nb);

        k_pack_scatter<<<npack + nchunk + ninit, 256, 0, stream>>>(
            cols, rows + half, cols + half, gcnt, col16, stage,
            (const float4*)user_embeds, dinv, (uint2*)f0,
            n_users, half, npack, nchunk, ninit, nb, n_u_elems / 4);

        k_brank2<<<nb, 256, 0, stream>>>(gcnt, stage, col16, rp, dinv,
                                         (const float4*)item_embeds, (uint2*)f0,
                                         n_users, n_items, n_edges, half, nb);
    }

    // ---- 3 merged propagation layers; 4 rows per wave ----
    {
        int nwaves = (n_nodes + 3) / 4;
        int sblocks = (nwaves * 64 + 255) / 256;
        k_spmm<<<sblocks, 256, 0, stream>>>(rp, col16, dinv,
                                            (const uint4*)f0, (uint4*)f1,
                                            (const uint4*)f0, (const uint4*)f0,
                                            (const float4*)user_embeds, (const float4*)item_embeds,
                                            (float4*)acc, n_users, n_nodes, 0);
        k_spmm<<<sblocks, 256, 0, stream>>>(rp, col16, dinv,
                                            (const uint4*)f1, (uint4*)f2,
                                            (const uint4*)f0, (const uint4*)f0,
                                            (const float4*)user_embeds, (const float4*)item_embeds,
                                            (float4*)acc, n_users, n_nodes, 0);
        k_spmm<<<sblocks, 256, 0, stream>>>(rp, col16, dinv,
                                            (const uint4*)f2, (uint4*)f0,
                                            (const uint4*)f1, (const uint4*)f2,
                                            (const float4*)user_embeds, (const float4*)item_embeds,
                                            (float4*)acc, n_users, n_nodes, 1);
    }
}

// Round 20
// 182.325 us; speedup vs baseline: 1.0452x; 1.0452x over previous
//
#include <hip/hip_runtime.h>

#define EMBED 64
#define IPB   128        // items per bucket (shift 7)
#define MAXNB 256        // max buckets (n_items/IPB = 196)
#define CHUNK 3200       // edges per scatter block (500 blocks)
#define EPT   13         // edges per thread in scatter (ceil(3200/256))
#define CAP   16384      // static per-bucket stage capacity (max real bucket ~8.5k)

// bf16 round-to-nearest-even helpers
__device__ __forceinline__ unsigned int bfr(float x) {
    unsigned int u = __float_as_uint(x);
    return (u + 0x7FFFu + ((u >> 16) & 1u)) >> 16;
}
__device__ __forceinline__ unsigned int pack2(float lo, float hi) {
    return bfr(lo) | (bfr(hi) << 16);
}

// ---------- build kernels ----------

// user rp + user dinv (two binary searches); also zeroes gcnt
__global__ void k_build1(const int* __restrict__ rows, int* __restrict__ rp,
                         float* __restrict__ dinv, int* __restrict__ gcnt,
                         int n_users, int half, int nb) {
    int r = blockIdx.x * blockDim.x + threadIdx.x;
    if (r < nb) gcnt[r] = 0;
    if (r > n_users) return;
    int lo = 0, hi = half;
    while (lo < hi) { int mid = (lo + hi) >> 1; if (rows[mid] < r) lo = mid + 1; else hi = mid; }
    rp[r] = lo;
    if (r < n_users) {
        int lo2 = lo, hi2 = half;
        while (lo2 < hi2) { int mid = (lo2 + hi2) >> 1; if (rows[mid] < r + 1) lo2 = mid + 1; else hi2 = mid; }
        int deg = lo2 - lo;
        dinv[r] = (deg > 0) ? (1.0f / sqrtf((float)deg)) : 0.0f;
    }
}

// fused 3-range kernel:
//  [0, npack)             : pack user-half cols -> u16
//  [npack, npack+nchunk)  : register-staged single-read scatter of item-half chunk
//  [npack+nchunk, +ninit) : user-row init f0 = dinv*e0 (bf16)
__global__ void k_pack_scatter(const int* __restrict__ cols,
                               const int* __restrict__ rows_hi, const int* __restrict__ cols_hi,
                               int* __restrict__ gcnt, unsigned short* __restrict__ col16,
                               unsigned int* __restrict__ stage,
                               const float4* __restrict__ u_emb, const float* __restrict__ dinv,
                               uint2* __restrict__ f0,
                               int n_users, int half, int npack, int nchunk, int ninit,
                               int nb, int n_u_vec) {
    int b = blockIdx.x;
    int tid = threadIdx.x;
    if (b < npack) {
        for (int e = b * 256 + tid; e < half; e += npack * 256)
            col16[e] = (unsigned short)(cols[e] - n_users);
        return;
    }
    b -= npack;
    if (b >= nchunk) {
        int bi = b - nchunk;
        for (int idx = bi * 256 + tid; idx < n_u_vec; idx += ninit * 256) {
            float4 v = u_emb[idx];
            float dv = dinv[idx >> 4];
            uint2 fv; fv.x = pack2(dv * v.x, dv * v.y); fv.y = pack2(dv * v.z, dv * v.w);
            f0[idx] = fv;
        }
        return;
    }
    // ---- scatter: pass A loads edges into registers + LDS histogram ----
    __shared__ int lh[MAXNB];
    __shared__ int cur[MAXNB];
    int beg = b * CHUNK;
    int end = beg + CHUNK; if (end > half) end = half;
    for (int i = tid; i < MAXNB; i += 256) lh[i] = 0;
    __syncthreads();
    unsigned int x[EPT];
    int nvalid = 0;
    #pragma unroll
    for (int k = 0; k < EPT; ++k) {
        int i = beg + tid + k * 256;
        if (i < end) {
            int it = rows_hi[i] - n_users;
            x[k] = ((unsigned int)it << 16) | (unsigned int)cols_hi[i];
            atomicAdd(&lh[it >> 7], 1);
            nvalid = k + 1;
        }
    }
    __syncthreads();
    if (tid < nb) {
        int c = lh[tid];
        int base = c ? atomicAdd(&gcnt[tid], c) : 0;
        cur[tid] = tid * CAP + base;
    }
    __syncthreads();
    // ---- pass B: scatter from registers ----
    #pragma unroll
    for (int k = 0; k < EPT; ++k) {
        if (k < nvalid) {
            int bk = x[k] >> 23;                 // item>>7
            int pos = atomicAdd(&cur[bk], 1);
            stage[pos] = x[k];
        }
    }
}

// one block per bucket: scan gcnt -> own base; hist 128 items; scan -> item rp +
// item dinv; rank into col16; then init this bucket's item rows (f0).
__global__ void k_brank2(const int* __restrict__ gcnt, const unsigned int* __restrict__ stage,
                         unsigned short* __restrict__ col16, int* __restrict__ rp,
                         float* __restrict__ dinv,
                         const float4* __restrict__ i_emb, uint2* __restrict__ f0,
                         int n_users, int n_items, int n_edges, int half, int nb) {
    __shared__ int sums[256];
    __shared__ int hist[IPB];
    __shared__ int scanbuf[IPB];
    __shared__ int cur[IPB];
    __shared__ float sdinv[IPB];
    int k = blockIdx.x;
    int tid = threadIdx.x;

    int v = (tid < nb) ? gcnt[tid] : 0;
    sums[tid] = v;
    __syncthreads();
    for (int o = 1; o < 256; o <<= 1) {
        int t = (tid >= o) ? sums[tid - o] : 0;
        __syncthreads();
        sums[tid] += t;
        __syncthreads();
    }
    int obase = half + sums[k] - gcnt[k];

    int first = k * IPB;
    int nit = n_items - first; if (nit > IPB) nit = IPB;
    int cnt = gcnt[k];
    int sbeg = k * CAP;

    if (tid < IPB) hist[tid] = 0;
    __syncthreads();
    for (int i = tid; i < cnt; i += 256)
        atomicAdd(&hist[(int)(stage[sbeg + i] >> 16) - first], 1);
    __syncthreads();
    if (tid < IPB) scanbuf[tid] = hist[tid];
    __syncthreads();
    for (int o = 1; o < IPB; o <<= 1) {
        int t = (tid < IPB && tid >= o) ? scanbuf[tid - o] : 0;
        __syncthreads();
        if (tid < IPB) scanbuf[tid] += t;
        __syncthreads();
    }
    if (tid < nit) {
        int pos = obase + scanbuf[tid] - hist[tid];
        rp[n_users + first + tid] = pos;
        cur[tid] = pos;
        int deg = hist[tid];
        float dv = (deg > 0) ? (1.0f / sqrtf((float)deg)) : 0.0f;
        dinv[n_users + first + tid] = dv;
        sdinv[tid] = dv;
    }
    if (k == 0 && tid == 0) rp[n_users + n_items] = n_edges;
    __syncthreads();
    for (int i = tid; i < cnt; i += 256) {
        unsigned int x = stage[sbeg + i];
        int il = (int)(x >> 16) - first;
        int pos = atomicAdd(&cur[il], 1);
        col16[pos] = (unsigned short)(x & 0xFFFFu);
    }
    // item-row init (f0 only)
    for (int t2 = tid; t2 < nit * 16; t2 += 256) {
        int i = t2 >> 4, q = t2 & 15;
        float4 v4 = i_emb[(size_t)(first + i) * 16 + q];
        float dv = sdinv[i];
        uint2 fv; fv.x = pack2(dv * v4.x, dv * v4.y); fv.y = pack2(dv * v4.z, dv * v4.w);
        f0[(size_t)(n_users + first + i) * 16 + q] = fv;
    }
}

// ---------- SpMM: EIGHT rows per wave (8-lane octets, serial edges) ----------
// per octet: sub = 8-dim slice 0..7; edges walked serially, unroll 4.
// No cross-lane reduction needed; all 8 lanes write the epilogue.
// last=0: fout[row] = bf16(dinv^2 * S)
// last=1: acc[row] = 0.25*(e0 + sqrt(deg)*(f1+f2) + dinv*S)
#define ACC8(sv, g) do { \
    sv[0] += __uint_as_float((g).x << 16); sv[1] += __uint_as_float((g).x & 0xFFFF0000u); \
    sv[2] += __uint_as_float((g).y << 16); sv[3] += __uint_as_float((g).y & 0xFFFF0000u); \
    sv[4] += __uint_as_float((g).z << 16); sv[5] += __uint_as_float((g).z & 0xFFFF0000u); \
    sv[6] += __uint_as_float((g).w << 16); sv[7] += __uint_as_float((g).w & 0xFFFF0000u); \
} while (0)

__global__ void k_spmm(const int* __restrict__ rp, const unsigned short* __restrict__ col16,
                       const float* __restrict__ dinv,
                       const uint4* __restrict__ fin, uint4* __restrict__ fout,
                       const uint4* __restrict__ fl1, const uint4* __restrict__ fl2,
                       const float4* __restrict__ u_emb, const float4* __restrict__ i_emb,
                       float4* __restrict__ acc,
                       int n_users, int n_nodes, int last) {
    int gid = blockIdx.x * blockDim.x + threadIdx.x;
    int wid = gid >> 6;                 // wave index
    int lane = threadIdx.x & 63;
    int oct  = lane >> 3;               // which row of the 8 (0..7)
    int sub  = lane & 7;                // 8-dim slice

    int row = wid * 8 + oct;
    if (row >= n_nodes) return;

    int beg = rp[row], end = rp[row + 1];
    unsigned int sbase = ((row < n_users) ? ((unsigned)n_users << 7) : 0u)
                       + ((unsigned)sub << 4);
    const char* fb = (const char*)fin;

    float s[8] = {0.f, 0.f, 0.f, 0.f, 0.f, 0.f, 0.f, 0.f};
    float t[8] = {0.f, 0.f, 0.f, 0.f, 0.f, 0.f, 0.f, 0.f};

    int j = beg;
    // 4 consecutive edges per iteration, all handled by this 8-lane octet
    for (; j + 3 < end; j += 4) {
        unsigned int c0 = col16[j];
        unsigned int c1 = col16[j + 1];
        unsigned int c2 = col16[j + 2];
        unsigned int c3 = col16[j + 3];
        uint4 g0 = *(const uint4*)(fb + ((c0 << 7) + sbase));
        uint4 g1 = *(const uint4*)(fb + ((c1 << 7) + sbase));
        uint4 g2 = *(const uint4*)(fb + ((c2 << 7) + sbase));
        uint4 g3 = *(const uint4*)(fb + ((c3 << 7) + sbase));
        ACC8(s, g0);
        ACC8(t, g1);
        ACC8(s, g2);
        ACC8(t, g3);
    }
    for (; j < end; ++j) {
        unsigned int c = col16[j];
        uint4 g = *(const uint4*)(fb + ((c << 7) + sbase));
        ACC8(s, g);
    }

    #pragma unroll
    for (int d = 0; d < 8; ++d) s[d] += t[d];
    // no cross-lane reduction: each octet-lane owns its 8 dims outright

    {
        float dv = dinv[row];
        if (!last) {
            float d2 = dv * dv;
            uint4 fn;
            fn.x = pack2(d2 * s[0], d2 * s[1]);
            fn.y = pack2(d2 * s[2], d2 * s[3]);
            fn.z = pack2(d2 * s[4], d2 * s[5]);
            fn.w = pack2(d2 * s[6], d2 * s[7]);
            fout[row * 8 + sub] = fn;
        } else {
            float sq = sqrtf((float)(end - beg));
            uint4 a = fl1[row * 8 + sub];
            uint4 b = fl2[row * 8 + sub];
            float e12[8];
            e12[0] = __uint_as_float(a.x << 16)         + __uint_as_float(b.x << 16);
            e12[1] = __uint_as_float(a.x & 0xFFFF0000u) + __uint_as_float(b.x & 0xFFFF0000u);
            e12[2] = __uint_as_float(a.y << 16)         + __uint_as_float(b.y << 16);
            e12[3] = __uint_as_float(a.y & 0xFFFF0000u) + __uint_as_float(b.y & 0xFFFF0000u);
            e12[4] = __uint_as_float(a.z << 16)         + __uint_as_float(b.z << 16);
            e12[5] = __uint_as_float(a.z & 0xFFFF0000u) + __uint_as_float(b.z & 0xFFFF0000u);
            e12[6] = __uint_as_float(a.w << 16)         + __uint_as_float(b.w << 16);
            e12[7] = __uint_as_float(a.w & 0xFFFF0000u) + __uint_as_float(b.w & 0xFFFF0000u);
            const float4* src = (row < n_users) ? u_emb : i_emb;
            int r0 = (row < n_users) ? row : row - n_users;
            float4 v0 = src[r0 * 16 + sub * 2];
            float4 v1 = src[r0 * 16 + sub * 2 + 1];
            float4 o0, o1;
            o0.x = 0.25f * (v0.x + sq * e12[0] + dv * s[0]);
            o0.y = 0.25f * (v0.y + sq * e12[1] + dv * s[1]);
            o0.z = 0.25f * (v0.z + sq * e12[2] + dv * s[2]);
            o0.w = 0.25f * (v0.w + sq * e12[3] + dv * s[3]);
            o1.x = 0.25f * (v1.x + sq * e12[4] + dv * s[4]);
            o1.y = 0.25f * (v1.y + sq * e12[5] + dv * s[5]);
            o1.z = 0.25f * (v1.z + sq * e12[6] + dv * s[6]);
            o1.w = 0.25f * (v1.w + sq * e12[7] + dv * s[7]);
            acc[row * 16 + sub * 2]     = o0;
            acc[row * 16 + sub * 2 + 1] = o1;
        }
    }
}

extern "C" void kernel_launch(void* const* d_in, const int* in_sizes, int n_in,
                              void* d_out, int out_size, void* d_ws, size_t ws_size,
                              hipStream_t stream) {
    const float* user_embeds = (const float*)d_in[0];
    const float* item_embeds = (const float*)d_in[1];
    const int*   rows        = (const int*)d_in[3];
    const int*   cols        = (const int*)d_in[4];

    const int n_u_elems = in_sizes[0];            // 50000*64
    const int n_i_elems = in_sizes[1];            // 25000*64
    const int n_total   = n_u_elems + n_i_elems;  // 75000*64
    const int n_edges   = in_sizes[2];            // 3,200,000
    const int half      = n_edges / 2;            // user-sorted half
    const int n_users   = n_u_elems / EMBED;      // 50000
    const int n_nodes   = n_total / EMBED;        // 75000
    const int n_items   = n_nodes - n_users;      // 25000
    const int nb        = (n_items + IPB - 1) / IPB;        // 196
    const int nchunk    = (half + CHUNK - 1) / CHUNK;       // 500
    const int npack     = 128;
    const int ninit     = 192;

    float* acc = (float*)d_out;

    char* p = (char*)d_ws;
    unsigned int* f0 = (unsigned int*)p;         p += (size_t)n_total * 2;   // bf16
    unsigned int* f1 = (unsigned int*)p;         p += (size_t)n_total * 2;
    unsigned int* f2 = (unsigned int*)p;         p += (size_t)n_total * 2;
    unsigned short* col16 = (unsigned short*)p;  p += (size_t)n_edges * 2;
    unsigned int* stage   = (unsigned int*)p;    p += (size_t)nb * CAP * 4;
    int*   rp     = (int*)p;                     p += (size_t)(n_nodes + 1) * 4;
    float* dinv   = (float*)p;                   p += (size_t)n_nodes * 4;
    int*   gcnt   = (int*)p;

    // ---- build + init: 3 dispatches ----
    {
        int ublocks = (n_users + 1 + 255) / 256;
        k_build1<<<ublocks, 256, 0, stream>>>(rows, rp, dinv, gcnt, n_users, half, nb);

        k_pack_scatter<<<npack + nchunk + ninit, 256, 0, stream>>>(
            cols, rows + half, cols + half, gcnt, col16, stage,
            (const float4*)user_embeds, dinv, (uint2*)f0,
            n_users, half, npack, nchunk, ninit, nb, n_u_elems / 4);

        k_brank2<<<nb, 256, 0, stream>>>(gcnt, stage, col16, rp, dinv,
                                         (const float4*)item_embeds, (uint2*)f0,
                                         n_users, n_items, n_edges, half, nb);
    }

    // ---- 3 merged propagation layers; 8 rows per wave ----
    {
        int nwaves = (n_nodes + 7) / 8;
        int sblocks = (nwaves * 64 + 255) / 256;
        k_spmm<<<sblocks, 256, 0, stream>>>(rp, col16, dinv,
                                            (const uint4*)f0, (uint4*)f1,
                                            (const uint4*)f0, (const uint4*)f0,
                                            (const float4*)user_embeds, (const float4*)item_embeds,
                                            (float4*)acc, n_users, n_nodes, 0);
        k_spmm<<<sblocks, 256, 0, stream>>>(rp, col16, dinv,
                                            (const uint4*)f1, (uint4*)f2,
                                            (const uint4*)f0, (const uint4*)f0,
                                            (const float4*)user_embeds, (const float4*)item_embeds,
                                            (float4*)acc, n_users, n_nodes, 0);
        k_spmm<<<sblocks, 256, 0, stream>>>(rp, col16, dinv,
                                            (const uint4*)f2, (uint4*)f0,
                                            (const uint4*)f1, (const uint4*)f2,
                                            (const float4*)user_embeds, (const float4*)item_embeds,
                                            (float4*)acc, n_users, n_nodes, 1);
    }
}

// Round 21
// 171.795 us; speedup vs baseline: 1.1093x; 1.0613x over previous
//
#include <hip/hip_runtime.h>

#define EMBED 64
#define IPB   128        // items per bucket (shift 7)
#define MAXNB 256        // max buckets (n_items/IPB = 196)
#define CHUNK 3200       // edges per scatter block (500 blocks)
#define EPT   13         // edges per thread in scatter (ceil(3200/256))
#define CAP   16384      // static per-bucket stage capacity (max real bucket ~8.5k)

// bf16 round-to-nearest-even helpers
__device__ __forceinline__ unsigned int bfr(float x) {
    unsigned int u = __float_as_uint(x);
    return (u + 0x7FFFu + ((u >> 16) & 1u)) >> 16;
}
__device__ __forceinline__ unsigned int pack2(float lo, float hi) {
    return bfr(lo) | (bfr(hi) << 16);
}

// ---------- build kernels ----------

// user rp + user dinv (two binary searches); also zeroes gcnt
__global__ void k_build1(const int* __restrict__ rows, int* __restrict__ rp,
                         float* __restrict__ dinv, int* __restrict__ gcnt,
                         int n_users, int half, int nb) {
    int r = blockIdx.x * blockDim.x + threadIdx.x;
    if (r < nb) gcnt[r] = 0;
    if (r > n_users) return;
    int lo = 0, hi = half;
    while (lo < hi) { int mid = (lo + hi) >> 1; if (rows[mid] < r) lo = mid + 1; else hi = mid; }
    rp[r] = lo;
    if (r < n_users) {
        int lo2 = lo, hi2 = half;
        while (lo2 < hi2) { int mid = (lo2 + hi2) >> 1; if (rows[mid] < r + 1) lo2 = mid + 1; else hi2 = mid; }
        int deg = lo2 - lo;
        dinv[r] = (deg > 0) ? (1.0f / sqrtf((float)deg)) : 0.0f;
    }
}

// fused 3-range kernel:
//  [0, npack)             : pack user-half cols -> u16
//  [npack, npack+nchunk)  : register-staged single-read scatter of item-half chunk
//  [npack+nchunk, +ninit) : user-row init f0 = dinv*e0 (bf16)
__global__ void k_pack_scatter(const int* __restrict__ cols,
                               const int* __restrict__ rows_hi, const int* __restrict__ cols_hi,
                               int* __restrict__ gcnt, unsigned short* __restrict__ col16,
                               unsigned int* __restrict__ stage,
                               const float4* __restrict__ u_emb, const float* __restrict__ dinv,
                               uint2* __restrict__ f0,
                               int n_users, int half, int npack, int nchunk, int ninit,
                               int nb, int n_u_vec) {
    int b = blockIdx.x;
    int tid = threadIdx.x;
    if (b < npack) {
        for (int e = b * 256 + tid; e < half; e += npack * 256)
            col16[e] = (unsigned short)(cols[e] - n_users);
        return;
    }
    b -= npack;
    if (b >= nchunk) {
        int bi = b - nchunk;
        for (int idx = bi * 256 + tid; idx < n_u_vec; idx += ninit * 256) {
            float4 v = u_emb[idx];
            float dv = dinv[idx >> 4];
            uint2 fv; fv.x = pack2(dv * v.x, dv * v.y); fv.y = pack2(dv * v.z, dv * v.w);
            f0[idx] = fv;
        }
        return;
    }
    // ---- scatter: pass A loads edges into registers + LDS histogram ----
    __shared__ int lh[MAXNB];
    __shared__ int cur[MAXNB];
    int beg = b * CHUNK;
    int end = beg + CHUNK; if (end > half) end = half;
    for (int i = tid; i < MAXNB; i += 256) lh[i] = 0;
    __syncthreads();
    unsigned int x[EPT];
    int nvalid = 0;
    #pragma unroll
    for (int k = 0; k < EPT; ++k) {
        int i = beg + tid + k * 256;
        if (i < end) {
            int it = rows_hi[i] - n_users;
            x[k] = ((unsigned int)it << 16) | (unsigned int)cols_hi[i];
            atomicAdd(&lh[it >> 7], 1);
            nvalid = k + 1;
        }
    }
    __syncthreads();
    if (tid < nb) {
        int c = lh[tid];
        int base = c ? atomicAdd(&gcnt[tid], c) : 0;
        cur[tid] = tid * CAP + base;
    }
    __syncthreads();
    // ---- pass B: scatter from registers ----
    #pragma unroll
    for (int k = 0; k < EPT; ++k) {
        if (k < nvalid) {
            int bk = x[k] >> 23;                 // item>>7
            int pos = atomicAdd(&cur[bk], 1);
            stage[pos] = x[k];
        }
    }
}

// one block per bucket: scan gcnt -> own base; hist 128 items; scan -> item rp +
// item dinv; rank into col16; then init this bucket's item rows (f0).
__global__ void k_brank2(const int* __restrict__ gcnt, const unsigned int* __restrict__ stage,
                         unsigned short* __restrict__ col16, int* __restrict__ rp,
                         float* __restrict__ dinv,
                         const float4* __restrict__ i_emb, uint2* __restrict__ f0,
                         int n_users, int n_items, int n_edges, int half, int nb) {
    __shared__ int sums[256];
    __shared__ int hist[IPB];
    __shared__ int scanbuf[IPB];
    __shared__ int cur[IPB];
    __shared__ float sdinv[IPB];
    int k = blockIdx.x;
    int tid = threadIdx.x;

    int v = (tid < nb) ? gcnt[tid] : 0;
    sums[tid] = v;
    __syncthreads();
    for (int o = 1; o < 256; o <<= 1) {
        int t = (tid >= o) ? sums[tid - o] : 0;
        __syncthreads();
        sums[tid] += t;
        __syncthreads();
    }
    int obase = half + sums[k] - gcnt[k];

    int first = k * IPB;
    int nit = n_items - first; if (nit > IPB) nit = IPB;
    int cnt = gcnt[k];
    int sbeg = k * CAP;

    if (tid < IPB) hist[tid] = 0;
    __syncthreads();
    for (int i = tid; i < cnt; i += 256)
        atomicAdd(&hist[(int)(stage[sbeg + i] >> 16) - first], 1);
    __syncthreads();
    if (tid < IPB) scanbuf[tid] = hist[tid];
    __syncthreads();
    for (int o = 1; o < IPB; o <<= 1) {
        int t = (tid < IPB && tid >= o) ? scanbuf[tid - o] : 0;
        __syncthreads();
        if (tid < IPB) scanbuf[tid] += t;
        __syncthreads();
    }
    if (tid < nit) {
        int pos = obase + scanbuf[tid] - hist[tid];
        rp[n_users + first + tid] = pos;
        cur[tid] = pos;
        int deg = hist[tid];
        float dv = (deg > 0) ? (1.0f / sqrtf((float)deg)) : 0.0f;
        dinv[n_users + first + tid] = dv;
        sdinv[tid] = dv;
    }
    if (k == 0 && tid == 0) rp[n_users + n_items] = n_edges;
    __syncthreads();
    for (int i = tid; i < cnt; i += 256) {
        unsigned int x = stage[sbeg + i];
        int il = (int)(x >> 16) - first;
        int pos = atomicAdd(&cur[il], 1);
        col16[pos] = (unsigned short)(x & 0xFFFFu);
    }
    // item-row init (f0 only)
    for (int t2 = tid; t2 < nit * 16; t2 += 256) {
        int i = t2 >> 4, q = t2 & 15;
        float4 v4 = i_emb[(size_t)(first + i) * 16 + q];
        float dv = sdinv[i];
        uint2 fv; fv.x = pack2(dv * v4.x, dv * v4.y); fv.y = pack2(dv * v4.z, dv * v4.w);
        f0[(size_t)(n_users + first + i) * 16 + q] = fv;
    }
}

// ---------- SpMM: FOUR rows per wave (16-lane quarters) ----------
// per quarter: grp = edge slot 0..1, sub = 8-dim slice 0..7
// last=0: fout[row] = bf16(dinv^2 * S)
// last=1: acc[row] = 0.25*(e0 + sqrt(deg)*(f1+f2) + dinv*S)
#define ACC8(sv, g) do { \
    sv[0] += __uint_as_float((g).x << 16); sv[1] += __uint_as_float((g).x & 0xFFFF0000u); \
    sv[2] += __uint_as_float((g).y << 16); sv[3] += __uint_as_float((g).y & 0xFFFF0000u); \
    sv[4] += __uint_as_float((g).z << 16); sv[5] += __uint_as_float((g).z & 0xFFFF0000u); \
    sv[6] += __uint_as_float((g).w << 16); sv[7] += __uint_as_float((g).w & 0xFFFF0000u); \
} while (0)

__global__ void k_spmm(const int* __restrict__ rp, const unsigned short* __restrict__ col16,
                       const float* __restrict__ dinv,
                       const uint4* __restrict__ fin, uint4* __restrict__ fout,
                       const uint4* __restrict__ fl1, const uint4* __restrict__ fl2,
                       const float4* __restrict__ u_emb, const float4* __restrict__ i_emb,
                       float4* __restrict__ acc,
                       int n_users, int n_nodes, int last) {
    int gid = blockIdx.x * blockDim.x + threadIdx.x;
    int wid = gid >> 6;                 // wave index
    int lane = threadIdx.x & 63;
    int qtr  = lane >> 4;               // which row of the quad (0..3)
    int grp  = (lane >> 3) & 1;         // edge slot 0..1
    int sub  = lane & 7;                // 8-dim slice

    int row = wid * 4 + qtr;
    if (row >= n_nodes) return;

    int beg = rp[row], end = rp[row + 1];
    unsigned int sbase = ((row < n_users) ? ((unsigned)n_users << 7) : 0u)
                       + ((unsigned)sub << 4);
    const char* fb = (const char*)fin;

    float s[8] = {0.f, 0.f, 0.f, 0.f, 0.f, 0.f, 0.f, 0.f};
    float t[8] = {0.f, 0.f, 0.f, 0.f, 0.f, 0.f, 0.f, 0.f};

    int j = beg + grp;
    // 8 consecutive edges per iteration (2 slots x stride-2 x unroll-4)
    for (; j + 6 < end; j += 8) {
        unsigned int c0 = col16[j];
        unsigned int c1 = col16[j + 2];
        unsigned int c2 = col16[j + 4];
        unsigned int c3 = col16[j + 6];
        uint4 g0 = *(const uint4*)(fb + ((c0 << 7) + sbase));
        uint4 g1 = *(const uint4*)(fb + ((c1 << 7) + sbase));
        uint4 g2 = *(const uint4*)(fb + ((c2 << 7) + sbase));
        uint4 g3 = *(const uint4*)(fb + ((c3 << 7) + sbase));
        ACC8(s, g0);
        ACC8(t, g1);
        ACC8(s, g2);
        ACC8(t, g3);
    }
    for (; j < end; j += 2) {
        unsigned int c = col16[j];
        uint4 g = *(const uint4*)(fb + ((c << 7) + sbase));
        ACC8(s, g);
    }

    #pragma unroll
    for (int d = 0; d < 8; ++d) s[d] += t[d];
    // reduce across the 2 edge slots (xor 8 stays within the 16-lane quarter)
    #pragma unroll
    for (int d = 0; d < 8; ++d) {
        s[d] += __shfl_xor(s[d], 8, 64);
    }

    if (grp == 0) {
        float dv = dinv[row];
        if (!last) {
            float d2 = dv * dv;
            uint4 fn;
            fn.x = pack2(d2 * s[0], d2 * s[1]);
            fn.y = pack2(d2 * s[2], d2 * s[3]);
            fn.z = pack2(d2 * s[4], d2 * s[5]);
            fn.w = pack2(d2 * s[6], d2 * s[7]);
            fout[row * 8 + sub] = fn;
        } else {
            float sq = sqrtf((float)(end - beg));
            uint4 a = fl1[row * 8 + sub];
            uint4 b = fl2[row * 8 + sub];
            float e12[8];
            e12[0] = __uint_as_float(a.x << 16)         + __uint_as_float(b.x << 16);
            e12[1] = __uint_as_float(a.x & 0xFFFF0000u) + __uint_as_float(b.x & 0xFFFF0000u);
            e12[2] = __uint_as_float(a.y << 16)         + __uint_as_float(b.y << 16);
            e12[3] = __uint_as_float(a.y & 0xFFFF0000u) + __uint_as_float(b.y & 0xFFFF0000u);
            e12[4] = __uint_as_float(a.z << 16)         + __uint_as_float(b.z << 16);
            e12[5] = __uint_as_float(a.z & 0xFFFF0000u) + __uint_as_float(b.z & 0xFFFF0000u);
            e12[6] = __uint_as_float(a.w << 16)         + __uint_as_float(b.w << 16);
            e12[7] = __uint_as_float(a.w & 0xFFFF0000u) + __uint_as_float(b.w & 0xFFFF0000u);
            const float4* src = (row < n_users) ? u_emb : i_emb;
            int r0 = (row < n_users) ? row : row - n_users;
            float4 v0 = src[r0 * 16 + sub * 2];
            float4 v1 = src[r0 * 16 + sub * 2 + 1];
            float4 o0, o1;
            o0.x = 0.25f * (v0.x + sq * e12[0] + dv * s[0]);
            o0.y = 0.25f * (v0.y + sq * e12[1] + dv * s[1]);
            o0.z = 0.25f * (v0.z + sq * e12[2] + dv * s[2]);
            o0.w = 0.25f * (v0.w + sq * e12[3] + dv * s[3]);
            o1.x = 0.25f * (v1.x + sq * e12[4] + dv * s[4]);
            o1.y = 0.25f * (v1.y + sq * e12[5] + dv * s[5]);
            o1.z = 0.25f * (v1.z + sq * e12[6] + dv * s[6]);
            o1.w = 0.25f * (v1.w + sq * e12[7] + dv * s[7]);
            acc[row * 16 + sub * 2]     = o0;
            acc[row * 16 + sub * 2 + 1] = o1;
        }
    }
}

extern "C" void kernel_launch(void* const* d_in, const int* in_sizes, int n_in,
                              void* d_out, int out_size, void* d_ws, size_t ws_size,
                              hipStream_t stream) {
    const float* user_embeds = (const float*)d_in[0];
    const float* item_embeds = (const float*)d_in[1];
    const int*   rows        = (const int*)d_in[3];
    const int*   cols        = (const int*)d_in[4];

    const int n_u_elems = in_sizes[0];            // 50000*64
    const int n_i_elems = in_sizes[1];            // 25000*64
    const int n_total   = n_u_elems + n_i_elems;  // 75000*64
    const int n_edges   = in_sizes[2];            // 3,200,000
    const int half      = n_edges / 2;            // user-sorted half
    const int n_users   = n_u_elems / EMBED;      // 50000
    const int n_nodes   = n_total / EMBED;        // 75000
    const int n_items   = n_nodes - n_users;      // 25000
    const int nb        = (n_items + IPB - 1) / IPB;        // 196
    const int nchunk    = (half + CHUNK - 1) / CHUNK;       // 500
    const int npack     = 128;
    const int ninit     = 192;

    float* acc = (float*)d_out;

    char* p = (char*)d_ws;
    unsigned int* f0 = (unsigned int*)p;         p += (size_t)n_total * 2;   // bf16
    unsigned int* f1 = (unsigned int*)p;         p += (size_t)n_total * 2;
    unsigned int* f2 = (unsigned int*)p;         p += (size_t)n_total * 2;
    unsigned short* col16 = (unsigned short*)p;  p += (size_t)n_edges * 2;
    unsigned int* stage   = (unsigned int*)p;    p += (size_t)nb * CAP * 4;
    int*   rp     = (int*)p;                     p += (size_t)(n_nodes + 1) * 4;
    float* dinv   = (float*)p;                   p += (size_t)n_nodes * 4;
    int*   gcnt   = (int*)p;

    // ---- build + init: 3 dispatches ----
    {
        int ublocks = (n_users + 1 + 255) / 256;
        k_build1<<<ublocks, 256, 0, stream>>>(rows, rp, dinv, gcnt, n_users, half, nb);

        k_pack_scatter<<<npack + nchunk + ninit, 256, 0, stream>>>(
            cols, rows + half, cols + half, gcnt, col16, stage,
            (const float4*)user_embeds, dinv, (uint2*)f0,
            n_users, half, npack, nchunk, ninit, nb, n_u_elems / 4);

        k_brank2<<<nb, 256, 0, stream>>>(gcnt, stage, col16, rp, dinv,
                                         (const float4*)item_embeds, (uint2*)f0,
                                         n_users, n_items, n_edges, half, nb);
    }

    // ---- 3 merged propagation layers; 4 rows per wave ----
    {
        int nwaves = (n_nodes + 3) / 4;
        int sblocks = (nwaves * 64 + 255) / 256;
        k_spmm<<<sblocks, 256, 0, stream>>>(rp, col16, dinv,
                                            (const uint4*)f0, (uint4*)f1,
                                            (const uint4*)f0, (const uint4*)f0,
                                            (const float4*)user_embeds, (const float4*)item_embeds,
                                            (float4*)acc, n_users, n_nodes, 0);
        k_spmm<<<sblocks, 256, 0, stream>>>(rp, col16, dinv,
                                            (const uint4*)f1, (uint4*)f2,
                                            (const uint4*)f0, (const uint4*)f0,
                                            (const float4*)user_embeds, (const float4*)item_embeds,
                                            (float4*)acc, n_users, n_nodes, 0);
        k_spmm<<<sblocks, 256, 0, stream>>>(rp, col16, dinv,
                                            (const uint4*)f2, (uint4*)f0,
                                            (const uint4*)f1, (const uint4*)f2,
                                            (const float4*)user_embeds, (const float4*)item_embeds,
                                            (float4*)acc, n_users, n_nodes, 1);
    }
}